// Round 13
// baseline (230.080 us; speedup 1.0000x reference)
//
#include <hip/hip_runtime.h>
#include <math.h>

#define BN 4096
#define DIM 256
#define D4 (DIM/4)        // 64 float4 per row
#define MI 8              // anchors per workgroup (fallback k_main)
#define MT 16             // anchors per workgroup (fused kernel)
#define MARGINF 0.3f
#define EPSF 1e-6f
#define SCAP 96           // staged class-member rows in k_pos (fallback)
#define IMAX 0x7fffffff

typedef __attribute__((ext_vector_type(8))) short bf16x8;
typedef __attribute__((ext_vector_type(4))) float f32x4;

__device__ __forceinline__ float fma4(float4 a, float4 b, float c){
  return fmaf(a.x,b.x, fmaf(a.y,b.y, fmaf(a.z,b.z, fmaf(a.w,b.w, c))));
}
__device__ __forceinline__ unsigned short f2bf(float x){   // RNE fp32 -> bf16
  unsigned u = __float_as_uint(x);
  return (unsigned short)((u + 0x7FFFu + ((u>>16)&1u)) >> 16);
}
__device__ __forceinline__ float bf2f(unsigned short h){
  return __uint_as_float(((unsigned)h)<<16);
}

// ======= FUSED kernel: convert -> device barrier -> mine -> GEMM -> loss =======
// 256 blocks x 1024 threads (16 waves, 4/SIMD; capacity 2 blocks/CU >= grid ->
// co-residency guaranteed for the spin barrier). Block b:
//  phase 0: converts its OWN 16 rows to fragment-tiled EhiT/EloT (global, for
//           other blocks' B loads) AND keeps them in LDS (its A fragments);
//           computes sq for its rows. Release-fence + counter barrier.
//  phase 1: fp32 hardest-positive mining (wave w = anchor w, d^2 space).
//  phase 2: single split-bf16 MFMA pass over all 4096 cols; hardest-neg +
//           first-semi selected in d^2 space (sqrt-free; monotone-equivalent).
//  phase 3: exact fp32 loss, per-block partial, last-block final reduce.
__global__ __launch_bounds__(1024,4) void k_fused(const float* __restrict__ E,
     unsigned short* __restrict__ EhiT, unsigned short* __restrict__ EloT,
     const int* __restrict__ labels, float* __restrict__ sq,
     float* __restrict__ partials, unsigned int* __restrict__ counters, float* __restrict__ out){
  __shared__ int   labsS[BN];         // 16 KB
  __shared__ float sqS[BN];           // 16 KB
  __shared__ bf16x8 afH[512];         // 8 KB  own A-hi fragments
  __shared__ bf16x8 afL[512];         // 8 KB  own A-lo fragments
  __shared__ float rnv[16][MT]; __shared__ int rnj[16][MT]; __shared__ int rsm[16][MT];
  __shared__ float apS[MT]; __shared__ int hpS[MT]; __shared__ int posOk[MT];
  __shared__ int finNeg[MT]; __shared__ int finVal[MT];
  __shared__ float lossS[MT];
  __shared__ float rs[16], rc[16];
  __shared__ int lastFlag;
  int t=threadIdx.x, l=t&63, w=t>>6;
  int lane16 = l&15, quad = l>>4;
  int a0 = blockIdx.x * MT;
  const float4* E4 = (const float4*)E;
  bf16x8* HT = (bf16x8*)EhiT;
  bf16x8* LT = (bf16x8*)EloT;
  size_t ABase = (size_t)blockIdx.x * 512;

  // ---------------- phase 0: convert own group + sq ----------------
  if (t < 512){
    int kk = t>>6, sub = t&63, q = sub>>4, n = sub&15;
    int row = a0 + n;                  // a0 = blockIdx*16
    int c = kk*4 + q;                  // 16B chunk within row (0..31)
    float4 v0 = E4[(size_t)row*64 + c*2];
    float4 v1 = E4[(size_t)row*64 + c*2 + 1];
    float vv[8] = {v0.x,v0.y,v0.z,v0.w, v1.x,v1.y,v1.z,v1.w};
    bf16x8 hv, lv;
    #pragma unroll
    for (int i=0;i<8;i++){
      unsigned short h = f2bf(vv[i]);
      hv[i] = (short)h;
      lv[i] = (short)f2bf(vv[i]-bf2f(h));
    }
    HT[ABase + t] = hv; LT[ABase + t] = lv;
    afH[t] = hv;        afL[t] = lv;
  }
  if (t < 64){
    int row = t>>2, part = t&3;
    const float4* rp = E4 + (size_t)(a0+row)*64 + part*16;
    float s0=0.f, s1=0.f;
    #pragma unroll
    for (int i=0;i<16;i+=2){ s0=fma4(rp[i],rp[i],s0); s1=fma4(rp[i+1],rp[i+1],s1); }
    float s = s0+s1;
    s += __shfl_xor(s,1); s += __shfl_xor(s,2);
    if (part==0) sq[a0+row] = s;
  }
  ((int4*)labsS)[t] = ((const int4*)labels)[t];    // input-only: pre-barrier ok
  __syncthreads();                                  // all block stores issued

  // ---------------- device-wide barrier (proven fence pattern) ----------------
  if (t==0){
    __threadfence();                                // release all block writes
    atomicAdd(&counters[0], 1u);
    while (__hip_atomic_load(&counters[0], __ATOMIC_RELAXED, __HIP_MEMORY_SCOPE_AGENT) < gridDim.x){
      __builtin_amdgcn_s_sleep(1);
    }
  }
  __syncthreads();
  __threadfence();                                  // acquire other blocks' writes

  // stage sq (now complete) to LDS
  ((float4*)sqS)[t] = ((const float4*)sq)[t];
  __syncthreads();
  float sqa[4]; int laba[4];
  #pragma unroll
  for (int r=0;r<4;r++){ sqa[r]=sqS[a0+quad*4+r]; laba[r]=labsS[a0+quad*4+r]; }

  // ======= phase 1: hardest positive (fp32, d^2 space), wave w = anchor a0+w =======
  {
    int aw = a0 + w;
    int labW = labsS[aw];
    float sqw_ = sqS[aw];
    float4 areg = E4[(size_t)aw*64 + l];
    float bv2 = -INFINITY; int bj = IMAX;
    for (int c=0; c<64; c++){                       // candidates ascending
      bool m = (labsS[c*64 + l] == labW);
      unsigned long long mask = __ballot(m);
      while (mask){
        int b = __ffsll((unsigned long long)mask) - 1;
        mask &= mask - 1ull;
        int j = c*64 + b;
        if (j == aw) continue;
        float4 bjv = E4[(size_t)j*64 + l];
        float p = fma4(areg, bjv, 0.0f);
        #pragma unroll
        for (int off=32; off; off>>=1) p += __shfl_xor(p, off);
        float d2 = sqw_ + sqS[j] - 2.0f*p;
        if (d2 > bv2){ bv2 = d2; bj = j; }          // j ascending: first max
      }
    }
    if (l==0){
      posOk[w] = (bj != IMAX);
      apS[w] = (bj==IMAX) ? -INFINITY : sqrtf(fmaxf(bv2, 0.0f));
      hpS[w] = (bj==IMAX) ? 0 : bj;
    }
  }
  __syncthreads();

  // ======= phase 2: single GEMM pass, hardest-neg + first-semi (d^2 space) =======
  {
    float ap2[4], th2[4];
    #pragma unroll
    for (int r=0;r<4;r++){
      float ap = apS[quad*4+r];
      ap2[r] = ap*ap;                               // +inf if no positive -> empty window
      float th = ap + MARGINF;
      th2[r] = th*th;
    }
    float mn[4]; int mj[4]; int sm[4];
    #pragma unroll
    for (int r=0;r<4;r++){ mn[r]=INFINITY; mj[r]=IMAX; sm[r]=IMAX; }
    #pragma unroll 1
    for (int tile=0; tile<16; tile++){
      int gb = w*16 + tile;
      size_t BBase = (size_t)gb * 512;
      f32x4 acc0={0.f,0.f,0.f,0.f}, acc1={0.f,0.f,0.f,0.f}, acc2={0.f,0.f,0.f,0.f};
      #pragma unroll 2
      for (int kk=0; kk<8; kk++){
        bf16x8 ah = afH[kk*64 + l];                 // LDS b128, lane-consecutive
        bf16x8 al = afL[kk*64 + l];
        bf16x8 bh = HT[BBase + kk*64 + l];          // global, lane-consecutive 1KB
        bf16x8 bl = LT[BBase + kk*64 + l];
        acc0 = __builtin_amdgcn_mfma_f32_16x16x32_bf16(ah, bh, acc0, 0,0,0);
        acc1 = __builtin_amdgcn_mfma_f32_16x16x32_bf16(ah, bl, acc1, 0,0,0);
        acc2 = __builtin_amdgcn_mfma_f32_16x16x32_bf16(al, bh, acc2, 0,0,0);
      }
      int j = gb*16 + lane16;
      int lj = labsS[j]; float sqj = sqS[j];
      #pragma unroll
      for (int r=0;r<4;r++){
        float dot = acc0[r] + (acc1[r] + acc2[r]);
        float d2v = sqa[r] + sqj - 2.0f*dot;        // sqrt-free: monotone-equivalent
        if (lj != laba[r]){
          if (d2v < mn[r]){ mn[r]=d2v; mj[r]=j; }               // j ascending: first min
          if (d2v > ap2[r] && d2v < th2[r] && j < sm[r]) sm[r]=j;
        }
      }
    }
    #pragma unroll
    for (int r=0;r<4;r++){
      float v=mn[r]; int j=mj[r]; int s=sm[r];
      #pragma unroll
      for (int off=1; off<16; off<<=1){
        float v2=__shfl_xor(v,off); int j2=__shfl_xor(j,off); int s2=__shfl_xor(s,off);
        if (v2<v || (v2==v && j2<j)){ v=v2; j=j2; }
        s = (s2<s)?s2:s;
      }
      if (lane16==0){ rnv[w][quad*4+r]=v; rnj[w][quad*4+r]=j; rsm[w][quad*4+r]=s; }
    }
  }
  __syncthreads();
  if (t < MT){
    int a=t;
    float V=INFINITY; int J=IMAX; int S=IMAX;
    for (int q=0;q<16;q++){                         // waves ascending = cols ascending
      float v2=rnv[q][a]; int j2=rnj[q][a];
      if (v2<V || (v2==V && j2<J)){ V=v2; J=j2; }
      int s2=rsm[q][a]; S=(s2<S)?s2:S;
    }
    bool anyneg = (J != IMAX);
    int ng = (S != IMAX) ? S : J;
    finNeg[a] = (ng==IMAX) ? 0 : ng;
    finVal[a] = (posOk[a] && anyneg) ? 1 : 0;
  }
  __syncthreads();

  // ------- phase 3: loss (fp32 exact), partials, last-block reduce -------
  {
    int a = w;
    float sp=0.f, sn=0.f;
    int dov = finVal[a];
    if (dov){
      int hp = hpS[a], ng = finNeg[a];
      float4 av = E4[(size_t)(a0+a)*64 + l];
      float4 pv = E4[(size_t)hp*64 + l];
      float4 nv = E4[(size_t)ng*64 + l];
      float d0=av.x-pv.x+EPSF, d1=av.y-pv.y+EPSF, d2=av.z-pv.z+EPSF, d3=av.w-pv.w+EPSF;
      sp = fmaf(d0,d0, fmaf(d1,d1, fmaf(d2,d2, d3*d3)));
      float n0=av.x-nv.x+EPSF, n1=av.y-nv.y+EPSF, n2=av.z-nv.z+EPSF, n3=av.w-nv.w+EPSF;
      sn = fmaf(n0,n0, fmaf(n1,n1, fmaf(n2,n2, n3*n3)));
    }
    #pragma unroll
    for (int off=32; off; off>>=1){ sp += __shfl_xor(sp,off); sn += __shfl_xor(sn,off); }
    if (l==0) lossS[a] = dov ? fmaxf(sqrtf(sp)-sqrtf(sn)+MARGINF, 0.0f) : 0.0f;
  }
  __syncthreads();
  if (t==0){
    float lsum=0.f, lcnt=0.f;
    for (int a=0;a<MT;a++){ lsum += lossS[a]; lcnt += (float)finVal[a]; }
    partials[2*blockIdx.x]   = lsum;
    partials[2*blockIdx.x+1] = lcnt;
    __threadfence();
    unsigned int old = atomicAdd(&counters[1], 1u);
    lastFlag = (old == gridDim.x - 1) ? 1 : 0;
  }
  __syncthreads();
  if (lastFlag){
    __threadfence();
    float s=0.f, c=0.f;
    if (t < 256){ s = partials[2*t]; c = partials[2*t+1]; }
    #pragma unroll
    for (int off=32; off; off>>=1){ s += __shfl_xor(s,off); c += __shfl_xor(c,off); }
    if (l==0){ rs[w]=s; rc[w]=c; }
    __syncthreads();
    if (t==0){
      float S=0.f, C=0.f;
      for (int q=0;q<16;q++){ S+=rs[q]; C+=rc[q]; }
      out[0] = (C>0.0f) ? S/fmaxf(C,1.0f) : 0.0f;
    }
  }
}

// ================= fallback path (small workspace) =================
__global__ __launch_bounds__(256) void k_sq(const float* __restrict__ E, float* __restrict__ sq){
  int i = blockIdx.x*256 + threadIdx.x;
  if (i >= BN) return;
  const float4* r = (const float4*)E + (size_t)i*D4;
  float a0=0.f,a1=0.f,a2=0.f,a3=0.f;
  #pragma unroll
  for (int q=0;q<D4;q+=4){
    a0 = fma4(r[q],r[q],a0);   a1 = fma4(r[q+1],r[q+1],a1);
    a2 = fma4(r[q+2],r[q+2],a2); a3 = fma4(r[q+3],r[q+3],a3);
  }
  sq[i] = (a0+a1)+(a2+a3);
}

__global__ __launch_bounds__(256) void k_pos(const float* __restrict__ E, const int* __restrict__ labels,
                       const float* __restrict__ sq, float* __restrict__ apw,
                       int* __restrict__ hpw, int* __restrict__ anypw){
  __shared__ int members[1024];
  __shared__ float4 mem4[SCAP*65];
  __shared__ int cnts[16][4];
  __shared__ int offs[16][4];
  __shared__ int cntS;
  int t = threadIdx.x, lane = t&63, w = t>>6;
  int c = blockIdx.x >> 2, split = blockIdx.x & 3;
  for (int ch=0; ch<16; ch++){
    bool m = (labels[ch*256 + t] == c);
    unsigned long long mask = __ballot(m);
    if (lane==0) cnts[ch][w] = __popcll(mask);
  }
  __syncthreads();
  if (t==0){
    int run=0;
    for (int ch=0; ch<16; ch++)
      for (int q=0;q<4;q++){ offs[ch][q]=run; run+=cnts[ch][q]; }
    cntS = run;
  }
  __syncthreads();
  int cnt = cntS; if (cnt>1024) cnt=1024;
  for (int ch=0; ch<16; ch++){
    int idx = ch*256 + t;
    bool m = (labels[idx] == c);
    unsigned long long mask = __ballot(m);
    int my = __popcll(mask & ((1ull<<lane)-1ull));
    int pos = offs[ch][w] + my;
    if (m && pos < 1024) members[pos] = idx;
  }
  int S = (cnt < SCAP) ? cnt : SCAP;
  int anyp = (cnt >= 2) ? 1 : 0;
  __syncthreads();
  const float4* E4 = (const float4*)E;
  for (int idx=t; idx<S*64; idx+=256){
    int row = idx>>6, f = idx&63;
    mem4[row*65 + f] = E4[(size_t)members[row]*D4 + f];
  }
  __syncthreads();
  int esplit = split*4 + w;
  int p = lane&3, cand = lane>>2;
  int passes = (cnt+15)>>4;
  for (int mi=esplit; mi<cnt; mi+=16){
    int i = members[mi];
    float sqi = sq[i];
    float4 ai4[16];
    if (mi < S){
      #pragma unroll
      for (int m=0;m<16;m++) ai4[m] = mem4[mi*65 + p + 4*m];
    } else {
      #pragma unroll
      for (int m=0;m<16;m++) ai4[m] = E4[(size_t)i*D4 + p + 4*m];
    }
    float bv = -INFINITY; int bj = IMAX;
    for (int ps=0; ps<passes; ps++){
      int mj = ps*16 + cand;
      if (mj < cnt && mj != mi){
        int j = members[mj];
        float a0v=0.f, a1v=0.f;
        if (mj < S){
          const float4* rj = mem4 + mj*65 + p;
          #pragma unroll
          for (int m=0;m<16;m+=2){ a0v=fma4(ai4[m],rj[4*m],a0v); a1v=fma4(ai4[m+1],rj[4*(m+1)],a1v); }
        } else {
          const float4* rj = E4 + (size_t)j*D4 + p;
          #pragma unroll
          for (int m=0;m<16;m+=2){ a0v=fma4(ai4[m],rj[4*m],a0v); a1v=fma4(ai4[m+1],rj[4*(m+1)],a1v); }
        }
        float acc = a0v+a1v;
        acc += __shfl_xor(acc,1); acc += __shfl_xor(acc,2);
        float d = sqrtf(fmaxf(sqi + sq[j] - 2.0f*acc, 0.0f));
        if (p==0){ if (d > bv || (d==bv && j<bj)){ bv=d; bj=j; } }
      }
    }
    #pragma unroll
    for (int off=32; off; off>>=1){
      float v2=__shfl_xor(bv,off); int j2=__shfl_xor(bj,off);
      if (v2>bv || (v2==bv && j2<bj)){ bv=v2; bj=j2; }
    }
    if (lane==0){
      int J = (bj==IMAX) ? 0 : bj;
      apw[i]=bv; hpw[i]=J; anypw[i]=anyp;
    }
  }
}

__global__ __launch_bounds__(256,2) void k_main(const float* __restrict__ E, const int* __restrict__ labels,
     const float* __restrict__ sq, const float* __restrict__ apw, const int* __restrict__ hpw,
     const int* __restrict__ anypw, float* __restrict__ partials){
  __shared__ float4 At[MI*68 + 4];
  __shared__ float redv[4][MI]; __shared__ int redj[4][MI]; __shared__ int redsm[4][MI];
  __shared__ int finNeg[MI]; __shared__ int finVal[MI];
  __shared__ float redp[4], redn[4];
  int t=threadIdx.x, lane=t&63, w=t>>6;
  int a0 = blockIdx.x * MI;
  const float4* E4 = (const float4*)E;
  for (int idx=t; idx<MI*64; idx+=256){
    int a=idx>>6, q=idx&63, pp=q&3, mm=q>>2;
    At[a*68 + pp*17 + mm] = E4[(size_t)(a0+a)*D4 + q];
  }
  __syncthreads();
  float apv[MI], sqi[MI]; int labi[MI];
  #pragma unroll
  for (int a=0;a<MI;a++){ apv[a]=apw[a0+a]; sqi[a]=sq[a0+a]; labi[a]=labels[a0+a]; }
  float mnv[MI]; int mnj[MI]; int smj[MI];
  #pragma unroll
  for (int a=0;a<MI;a++){ mnv[a]=INFINITY; mnj[a]=0; smj[a]=IMAX; }
  int s = t>>2, p = t&3;
  for (int it=0; it<16; it++){
    int colb = it*256 + 4*s;
    const float4* __restrict__ bp = E4 + (size_t)colb*D4 + p;
    float acc[MI][4];
    #pragma unroll
    for (int a=0;a<MI;a++){
      #pragma unroll
      for (int c2=0;c2<4;c2++) acc[a][c2]=0.0f;
    }
    for (int mg=0; mg<4; mg++){
      float4 b[4][4];
      #pragma unroll
      for (int c2=0;c2<4;c2++){
        #pragma unroll
        for (int m=0;m<4;m++) b[m][c2] = bp[(size_t)c2*D4 + mg*16 + m*4];
      }
      #pragma unroll
      for (int a=0;a<MI;a++){
        float4 a4[4];
        #pragma unroll
        for (int m=0;m<4;m++) a4[m] = At[a*68 + p*17 + mg*4 + m];
        #pragma unroll
        for (int m=0;m<4;m++){
          #pragma unroll
          for (int c2=0;c2<4;c2++) acc[a][c2] = fma4(a4[m], b[m][c2], acc[a][c2]);
        }
      }
    }
    #pragma unroll
    for (int a=0;a<MI;a++){
      #pragma unroll
      for (int c2=0;c2<4;c2++){
        float v = acc[a][c2];
        v += __shfl_xor(v,1); v += __shfl_xor(v,2);
        acc[a][c2] = v;
      }
    }
    #pragma unroll
    for (int c2=0;c2<4;c2++){
      int j = colb + c2;
      int lj = labels[j]; float sqj = sq[j];
      #pragma unroll
      for (int a=0;a<MI;a++){
        float d = sqrtf(fmaxf(sqi[a]+sqj-2.0f*acc[a][c2], 0.0f));
        if (lj != labi[a]){
          if (d < mnv[a]){ mnv[a]=d; mnj[a]=j; }
          if (d > apv[a] && d < apv[a]+MARGINF && j < smj[a]) smj[a]=j;
        }
      }
    }
  }
  #pragma unroll
  for (int a=0;a<MI;a++){
    float v=mnv[a]; int j=mnj[a]; int sm=smj[a];
    #pragma unroll
    for (int off=32; off; off>>=1){
      float v2=__shfl_xor(v,off); int j2=__shfl_xor(j,off); int s2=__shfl_xor(sm,off);
      if (v2<v || (v2==v && j2<j)){ v=v2; j=j2; }
      sm = (s2<sm)?s2:sm;
    }
    if (lane==0){ redv[w][a]=v; redj[w][a]=j; redsm[w][a]=sm; }
  }
  __syncthreads();
  if (t < MI){
    int a=t;
    float V=INFINITY; int J=0; int S=IMAX; bool first=true;
    for (int q=0;q<4;q++){
      float v2=redv[q][a]; int j2=redj[q][a];
      if (first || v2<V || (v2==V && j2<J)){ V=v2; J=j2; first=false; }
      int s2=redsm[q][a]; S=(s2<S)?s2:S;
    }
    bool anyneg = (V < INFINITY);
    finNeg[a] = (S != IMAX) ? S : J;
    finVal[a] = (anypw[a0+a] != 0 && anyneg) ? 1 : 0;
  }
  __syncthreads();
  float lsum=0.0f, lcnt=0.0f;
  for (int a=0;a<MI;a++){
    if (finVal[a]){
      int hp = hpw[a0+a]; int ng = finNeg[a];
      float ai = E[(size_t)(a0+a)*DIM + t];
      float pv = E[(size_t)hp*DIM + t];
      float nv = E[(size_t)ng*DIM + t];
      float dp = ai - pv + EPSF; float dn = ai - nv + EPSF;
      float sp = dp*dp, sn = dn*dn;
      #pragma unroll
      for (int off=32; off; off>>=1){ sp += __shfl_xor(sp,off); sn += __shfl_xor(sn,off); }
      if (lane==0){ redp[w]=sp; redn[w]=sn; }
    }
    __syncthreads();
    if (finVal[a] && t==0){
      float SP=(redp[0]+redp[1])+(redp[2]+redp[3]);
      float SN=(redn[0]+redn[1])+(redn[2]+redn[3]);
      lsum += fmaxf(sqrtf(SP)-sqrtf(SN)+MARGINF, 0.0f);
      lcnt += 1.0f;
    }
    __syncthreads();
  }
  if (t==0){ partials[2*blockIdx.x]=lsum; partials[2*blockIdx.x+1]=lcnt; }
}

__global__ __launch_bounds__(256) void k_fin(const float* __restrict__ partials, float* __restrict__ out, int nb){
  __shared__ float rs[4], rc[4];
  int t=threadIdx.x, lane=t&63, w=t>>6;
  float s=0.f, c=0.f;
  for (int q=t;q<nb;q+=256){ s+=partials[2*q]; c+=partials[2*q+1]; }
  #pragma unroll
  for (int off=32; off; off>>=1){ s+=__shfl_xor(s,off); c+=__shfl_xor(c,off); }
  if (lane==0){ rs[w]=s; rc[w]=c; }
  __syncthreads();
  if (t==0){
    float S=(rs[0]+rs[1])+(rs[2]+rs[3]);
    float C=(rc[0]+rc[1])+(rc[2]+rc[3]);
    out[0] = (C>0.0f) ? S/fmaxf(C,1.0f) : 0.0f;
  }
}

extern "C" void kernel_launch(void* const* d_in, const int* in_sizes, int n_in,
                              void* d_out, int out_size, void* d_ws, size_t ws_size,
                              hipStream_t stream) {
  const float* E      = (const float*)d_in[0];   // 4096x256 fp32
  const int*   labels = (const int*)d_in[1];     // 4096 int32
  float* out = (float*)d_out;

  bool big = ws_size >= (size_t)(131072 + 4*1024*1024);
  if (big){
    // big-path layout: counters at 0 (2 uints), sq at +256, partials after
    unsigned int* counters = (unsigned int*)d_ws;
    float* sqw      = (float*)((char*)d_ws + 256);          // 4096 f
    float* partials = sqw + BN;                              // 512 f
    unsigned short* EhiT = (unsigned short*)((char*)d_ws + 131072);   // 2 MB (tiled)
    unsigned short* EloT = EhiT + (size_t)BN*DIM;                     // 2 MB (tiled)
    hipMemsetAsync(d_ws, 0, 8, stream);          // zero both counters (graph-safe)
    k_fused<<<BN/MT, 1024, 0, stream>>>(E, EhiT, EloT, labels, sqw, partials, counters, out);
  } else {
    float* sqw      = (float*)d_ws;          // 4096 f
    float* apw      = sqw + BN;              // 4096 f
    int*   hpw      = (int*)(apw + BN);      // 4096 i
    int*   anypw    = hpw + BN;              // 4096 i
    float* partials = (float*)(anypw + BN);  // 1024 f
    k_sq  <<<BN/256, 256, 0, stream>>>(E, sqw);
    k_pos <<<256,    256, 0, stream>>>(E, labels, sqw, apw, hpw, anypw);
    k_main<<<BN/MI,  256, 0, stream>>>(E, labels, sqw, apw, hpw, anypw, partials);
    k_fin <<<1,      256, 0, stream>>>(partials, out, BN/MI);
  }
}

// Round 14
// 154.919 us; speedup vs baseline: 1.4852x; 1.4852x over previous
//
#include <hip/hip_runtime.h>
#include <math.h>

#define BN 4096
#define DIM 256
#define D4 (DIM/4)        // 64 float4 per row
#define MI 8              // anchors per workgroup (fallback k_main)
#define MT 16             // anchors per workgroup (MFMA-path k_main_m)
#define MARGINF 0.3f
#define EPSF 1e-6f
#define SCAP 96           // staged class-member rows in k_pos (fallback)
#define IMAX 0x7fffffff

typedef __attribute__((ext_vector_type(8))) short bf16x8;
typedef __attribute__((ext_vector_type(4))) float f32x4;

__device__ __forceinline__ float fma4(float4 a, float4 b, float c){
  return fmaf(a.x,b.x, fmaf(a.y,b.y, fmaf(a.z,b.z, fmaf(a.w,b.w, c))));
}
__device__ __forceinline__ unsigned short f2bf(float x){   // RNE fp32 -> bf16
  unsigned u = __float_as_uint(x);
  return (unsigned short)((u + 0x7FFFu + ((u>>16)&1u)) >> 16);
}
__device__ __forceinline__ float bf2f(unsigned short h){
  return __uint_as_float(((unsigned)h)<<16);
}

// ------- kernel A: E -> EhiT/EloT in FRAGMENT-TILED layout, per-row sq -------
// Tiled layout (16B units): idx16 = g*512 + kk*64 + lane, holding row
// g*16+(lane&15), k-elements kk*32+(lane>>4)*8 .. +8. A wave's fragment load
// for (g,kk) is then base + lane*16B: 64 lanes x 16B CONSECUTIVE (TA fast path).
__global__ __launch_bounds__(256) void k_pre2(const float* __restrict__ E,
     unsigned short* __restrict__ EhiT, unsigned short* __restrict__ EloT,
     float* __restrict__ sq, unsigned int* __restrict__ counter){
  int t = threadIdx.x;
  int b = blockIdx.x;                 // 64 blocks: rows b*64..+63 = groups b*4..+3
  const float4* E4 = (const float4*)E;
  bf16x8* HT = (bf16x8*)EhiT;
  bf16x8* LT = (bf16x8*)EloT;
  #pragma unroll
  for (int it=0; it<8; it++){
    int g  = b*4 + (it>>1);
    int kk = (it&1)*4 + (t>>6);
    int sub = t&63, q = sub>>4, n = sub&15;
    int r = g*16 + n;
    int c = kk*4 + q;                 // 16B chunk within row (0..31)
    float4 v0 = E4[(size_t)r*64 + c*2];
    float4 v1 = E4[(size_t)r*64 + c*2 + 1];
    unsigned short h[8], lo[8];
    float vv[8] = {v0.x,v0.y,v0.z,v0.w, v1.x,v1.y,v1.z,v1.w};
    #pragma unroll
    for (int i=0;i<8;i++){ h[i]=f2bf(vv[i]); lo[i]=f2bf(vv[i]-bf2f(h[i])); }
    bf16x8 hv, lv;
    #pragma unroll
    for (int i=0;i<8;i++){ hv[i]=(short)h[i]; lv[i]=(short)lo[i]; }
    size_t d = (size_t)g*512 + (size_t)kk*64 + sub;   // writes lane-consecutive
    HT[d] = hv; LT[d] = lv;
  }
  // per-row squared norm (4 lanes per row, fp32 exact from E)
  int row = t>>2, part = t&3;
  const float4* rp = E4 + (size_t)(b*64+row)*D4 + part*16;
  float s0=0.f, s1=0.f;
  #pragma unroll
  for (int i=0;i<16;i+=2){ s0=fma4(rp[i],rp[i],s0); s1=fma4(rp[i+1],rp[i+1],s1); }
  float s = s0+s1;
  s += __shfl_xor(s,1); s += __shfl_xor(s,2);
  if (part==0) sq[b*64+row] = s;
  if (b==0 && t==0) counter[0] = 0u;
}

// ------- kernel B: fp32 pos-mining + SINGLE split-bf16 MFMA pass + loss -------
// 256 blocks x 1024 threads (16 waves, 4/SIMD). Block = 16 anchors x 4096 cols.
// Round-12 structure (fusion with device barrier regressed — round 13), plus
// the d^2-space selection validated in round 13: sqrt-free mining + selection
// (monotone-equivalent; one sqrt per anchor survives to form ap).
__global__ __launch_bounds__(1024,4) void k_main_m(const float* __restrict__ E,
     const unsigned short* __restrict__ EhiT, const unsigned short* __restrict__ EloT,
     const int* __restrict__ labels, const float* __restrict__ sq,
     float* __restrict__ partials, unsigned int* __restrict__ counter, float* __restrict__ out){
  __shared__ int   labsS[BN];         // 16 KB
  __shared__ float sqS[BN];           // 16 KB
  __shared__ bf16x8 afH[512];         // 8 KB  A-hi fragments (16B units)
  __shared__ bf16x8 afL[512];         // 8 KB  A-lo fragments
  __shared__ float rnv[16][MT]; __shared__ int rnj[16][MT]; __shared__ int rsm[16][MT];
  __shared__ float apS[MT]; __shared__ int hpS[MT]; __shared__ int posOk[MT];
  __shared__ int finNeg[MT]; __shared__ int finVal[MT];
  __shared__ float lossS[MT];
  __shared__ float rs[16], rc[16];
  __shared__ int lastFlag;
  int t=threadIdx.x, l=t&63, w=t>>6;
  int lane16 = l&15, quad = l>>4;
  int a0 = blockIdx.x * MT;
  const bf16x8* HT = (const bf16x8*)EhiT;
  const bf16x8* LT = (const bf16x8*)EloT;
  const float4* E4 = (const float4*)E;
  size_t ABase = (size_t)blockIdx.x * 512;       // anchor group = blockIdx

  // stage labels+sq+A-fragments to LDS (all coalesced)
  ((int4*)labsS)[t]  = ((const int4*)labels)[t];
  ((float4*)sqS)[t]  = ((const float4*)sq)[t];
  if (t < 512){ afH[t] = HT[ABase + t]; afL[t] = LT[ABase + t]; }
  __syncthreads();
  float sqa[4]; int laba[4];
  #pragma unroll
  for (int r=0;r<4;r++){ sqa[r]=sqS[a0+quad*4+r]; laba[r]=labsS[a0+quad*4+r]; }

  // ======= hardest positive: fp32 mining in d^2 space, wave w = anchor a0+w =======
  {
    int aw = a0 + w;
    int labW = labsS[aw];
    float sqw_ = sqS[aw];
    float4 areg = E4[(size_t)aw*64 + l];         // lane l: dims 4l..4l+3
    float bv2 = -INFINITY; int bj = IMAX;
    for (int c=0; c<64; c++){                    // candidates ascending
      bool m = (labsS[c*64 + l] == labW);
      unsigned long long mask = __ballot(m);
      while (mask){
        int b = __ffsll((unsigned long long)mask) - 1;
        mask &= mask - 1ull;
        int j = c*64 + b;
        if (j == aw) continue;
        float4 bjv = E4[(size_t)j*64 + l];       // coalesced 256B row read
        float p = fma4(areg, bjv, 0.0f);
        #pragma unroll
        for (int off=32; off; off>>=1) p += __shfl_xor(p, off);
        float d2 = sqw_ + sqS[j] - 2.0f*p;       // sqrt-free (monotone)
        if (d2 > bv2){ bv2 = d2; bj = j; }       // j ascending: first max
      }
    }
    if (l==0){
      posOk[w] = (bj != IMAX);
      apS[w] = (bj==IMAX) ? -INFINITY : sqrtf(fmaxf(bv2, 0.0f));  // one sqrt/anchor
      hpS[w] = (bj==IMAX) ? 0 : bj;
    }
  }
  __syncthreads();

  // ======= single GEMM pass: hardest-neg + first semi-hard (d^2 space) =======
  {
    float ap2[4], th2[4];
    #pragma unroll
    for (int r=0;r<4;r++){
      float ap = apS[quad*4+r];
      ap2[r] = ap*ap;                            // +inf window stays empty if no positive
      float th = ap + MARGINF;
      th2[r] = th*th;
    }
    float mn[4]; int mj[4]; int sm[4];
    #pragma unroll
    for (int r=0;r<4;r++){ mn[r]=INFINITY; mj[r]=IMAX; sm[r]=IMAX; }
    #pragma unroll 1
    for (int tile=0; tile<16; tile++){
      int gb = w*16 + tile;
      size_t BBase = (size_t)gb * 512;
      f32x4 acc0={0.f,0.f,0.f,0.f}, acc1={0.f,0.f,0.f,0.f}, acc2={0.f,0.f,0.f,0.f};
      #pragma unroll 2
      for (int kk=0; kk<8; kk++){
        bf16x8 ah = afH[kk*64 + l];              // LDS b128, lane-consecutive
        bf16x8 al = afL[kk*64 + l];
        bf16x8 bh = HT[BBase + kk*64 + l];       // global, lane-consecutive 1KB
        bf16x8 bl = LT[BBase + kk*64 + l];
        acc0 = __builtin_amdgcn_mfma_f32_16x16x32_bf16(ah, bh, acc0, 0,0,0);
        acc1 = __builtin_amdgcn_mfma_f32_16x16x32_bf16(ah, bl, acc1, 0,0,0);
        acc2 = __builtin_amdgcn_mfma_f32_16x16x32_bf16(al, bh, acc2, 0,0,0);
      }
      int j = gb*16 + lane16;
      int lj = labsS[j]; float sqj = sqS[j];
      #pragma unroll
      for (int r=0;r<4;r++){
        float dot = acc0[r] + (acc1[r] + acc2[r]);
        float d2v = sqa[r] + sqj - 2.0f*dot;     // sqrt-free: monotone-equivalent
        if (lj != laba[r]){
          if (d2v < mn[r]){ mn[r]=d2v; mj[r]=j; }               // j ascending: first min
          if (d2v > ap2[r] && d2v < th2[r] && j < sm[r]) sm[r]=j;
        }
      }
    }
    #pragma unroll
    for (int r=0;r<4;r++){
      float v=mn[r]; int j=mj[r]; int s=sm[r];
      #pragma unroll
      for (int off=1; off<16; off<<=1){
        float v2=__shfl_xor(v,off); int j2=__shfl_xor(j,off); int s2=__shfl_xor(s,off);
        if (v2<v || (v2==v && j2<j)){ v=v2; j=j2; }
        s = (s2<s)?s2:s;
      }
      if (lane16==0){ rnv[w][quad*4+r]=v; rnj[w][quad*4+r]=j; rsm[w][quad*4+r]=s; }
    }
  }
  __syncthreads();
  if (t < MT){
    int a=t;
    float V=INFINITY; int J=IMAX; int S=IMAX;
    for (int q=0;q<16;q++){                      // waves ascending = cols ascending
      float v2=rnv[q][a]; int j2=rnj[q][a];
      if (v2<V || (v2==V && j2<J)){ V=v2; J=j2; }
      int s2=rsm[q][a]; S=(s2<S)?s2:S;
    }
    bool anyneg = (J != IMAX);
    int ng = (S != IMAX) ? S : J;
    finNeg[a] = (ng==IMAX) ? 0 : ng;
    finVal[a] = (posOk[a] && anyneg) ? 1 : 0;
  }
  __syncthreads();

  // ------- loss epilogue: wave w owns anchor w (fp32 exact, 1 barrier) -------
  {
    int a = w;
    float sp=0.f, sn=0.f;
    int dov = finVal[a];
    if (dov){
      int hp = hpS[a], ng = finNeg[a];
      float4 av = E4[(size_t)(a0+a)*64 + l];
      float4 pv = E4[(size_t)hp*64 + l];
      float4 nv = E4[(size_t)ng*64 + l];
      float d0=av.x-pv.x+EPSF, d1=av.y-pv.y+EPSF, d2=av.z-pv.z+EPSF, d3=av.w-pv.w+EPSF;
      sp = fmaf(d0,d0, fmaf(d1,d1, fmaf(d2,d2, d3*d3)));
      float n0=av.x-nv.x+EPSF, n1=av.y-nv.y+EPSF, n2=av.z-nv.z+EPSF, n3=av.w-nv.w+EPSF;
      sn = fmaf(n0,n0, fmaf(n1,n1, fmaf(n2,n2, n3*n3)));
    }
    #pragma unroll
    for (int off=32; off; off>>=1){ sp += __shfl_xor(sp,off); sn += __shfl_xor(sn,off); }
    if (l==0) lossS[a] = dov ? fmaxf(sqrtf(sp)-sqrtf(sn)+MARGINF, 0.0f) : 0.0f;
  }
  __syncthreads();

  // ------- per-block partial + last-block final reduce -------
  if (t==0){
    float lsum=0.f, lcnt=0.f;
    for (int a=0;a<MT;a++){ lsum += lossS[a]; lcnt += (float)finVal[a]; }
    partials[2*blockIdx.x]   = lsum;
    partials[2*blockIdx.x+1] = lcnt;
    __threadfence();
    unsigned int old = atomicAdd(counter, 1u);
    lastFlag = (old == gridDim.x - 1) ? 1 : 0;
  }
  __syncthreads();
  if (lastFlag){
    __threadfence();
    float s=0.f, c=0.f;
    if (t < 256){ s = partials[2*t]; c = partials[2*t+1]; }
    #pragma unroll
    for (int off=32; off; off>>=1){ s += __shfl_xor(s,off); c += __shfl_xor(c,off); }
    if (l==0){ rs[w]=s; rc[w]=c; }
    __syncthreads();
    if (t==0){
      float S=0.f, C=0.f;
      for (int q=0;q<16;q++){ S+=rs[q]; C+=rc[q]; }
      out[0] = (C>0.0f) ? S/fmaxf(C,1.0f) : 0.0f;
    }
  }
}

// ================= fallback path (small workspace) =================
__global__ __launch_bounds__(256) void k_sq(const float* __restrict__ E, float* __restrict__ sq){
  int i = blockIdx.x*256 + threadIdx.x;
  if (i >= BN) return;
  const float4* r = (const float4*)E + (size_t)i*D4;
  float a0=0.f,a1=0.f,a2=0.f,a3=0.f;
  #pragma unroll
  for (int q=0;q<D4;q+=4){
    a0 = fma4(r[q],r[q],a0);   a1 = fma4(r[q+1],r[q+1],a1);
    a2 = fma4(r[q+2],r[q+2],a2); a3 = fma4(r[q+3],r[q+3],a3);
  }
  sq[i] = (a0+a1)+(a2+a3);
}

__global__ __launch_bounds__(256) void k_pos(const float* __restrict__ E, const int* __restrict__ labels,
                       const float* __restrict__ sq, float* __restrict__ apw,
                       int* __restrict__ hpw, int* __restrict__ anypw){
  __shared__ int members[1024];
  __shared__ float4 mem4[SCAP*65];
  __shared__ int cnts[16][4];
  __shared__ int offs[16][4];
  __shared__ int cntS;
  int t = threadIdx.x, lane = t&63, w = t>>6;
  int c = blockIdx.x >> 2, split = blockIdx.x & 3;
  for (int ch=0; ch<16; ch++){
    bool m = (labels[ch*256 + t] == c);
    unsigned long long mask = __ballot(m);
    if (lane==0) cnts[ch][w] = __popcll(mask);
  }
  __syncthreads();
  if (t==0){
    int run=0;
    for (int ch=0; ch<16; ch++)
      for (int q=0;q<4;q++){ offs[ch][q]=run; run+=cnts[ch][q]; }
    cntS = run;
  }
  __syncthreads();
  int cnt = cntS; if (cnt>1024) cnt=1024;
  for (int ch=0; ch<16; ch++){
    int idx = ch*256 + t;
    bool m = (labels[idx] == c);
    unsigned long long mask = __ballot(m);
    int my = __popcll(mask & ((1ull<<lane)-1ull));
    int pos = offs[ch][w] + my;
    if (m && pos < 1024) members[pos] = idx;
  }
  int S = (cnt < SCAP) ? cnt : SCAP;
  int anyp = (cnt >= 2) ? 1 : 0;
  __syncthreads();
  const float4* E4 = (const float4*)E;
  for (int idx=t; idx<S*64; idx+=256){
    int row = idx>>6, f = idx&63;
    mem4[row*65 + f] = E4[(size_t)members[row]*D4 + f];
  }
  __syncthreads();
  int esplit = split*4 + w;
  int p = lane&3, cand = lane>>2;
  int passes = (cnt+15)>>4;
  for (int mi=esplit; mi<cnt; mi+=16){
    int i = members[mi];
    float sqi = sq[i];
    float4 ai4[16];
    if (mi < S){
      #pragma unroll
      for (int m=0;m<16;m++) ai4[m] = mem4[mi*65 + p + 4*m];
    } else {
      #pragma unroll
      for (int m=0;m<16;m++) ai4[m] = E4[(size_t)i*D4 + p + 4*m];
    }
    float bv = -INFINITY; int bj = IMAX;
    for (int ps=0; ps<passes; ps++){
      int mj = ps*16 + cand;
      if (mj < cnt && mj != mi){
        int j = members[mj];
        float a0v=0.f, a1v=0.f;
        if (mj < S){
          const float4* rj = mem4 + mj*65 + p;
          #pragma unroll
          for (int m=0;m<16;m+=2){ a0v=fma4(ai4[m],rj[4*m],a0v); a1v=fma4(ai4[m+1],rj[4*(m+1)],a1v); }
        } else {
          const float4* rj = E4 + (size_t)j*D4 + p;
          #pragma unroll
          for (int m=0;m<16;m+=2){ a0v=fma4(ai4[m],rj[4*m],a0v); a1v=fma4(ai4[m+1],rj[4*(m+1)],a1v); }
        }
        float acc = a0v+a1v;
        acc += __shfl_xor(acc,1); acc += __shfl_xor(acc,2);
        float d = sqrtf(fmaxf(sqi + sq[j] - 2.0f*acc, 0.0f));
        if (p==0){ if (d > bv || (d==bv && j<bj)){ bv=d; bj=j; } }
      }
    }
    #pragma unroll
    for (int off=32; off; off>>=1){
      float v2=__shfl_xor(bv,off); int j2=__shfl_xor(bj,off);
      if (v2>bv || (v2==bv && j2<bj)){ bv=v2; bj=j2; }
    }
    if (lane==0){
      int J = (bj==IMAX) ? 0 : bj;
      apw[i]=bv; hpw[i]=J; anypw[i]=anyp;
    }
  }
}

__global__ __launch_bounds__(256,2) void k_main(const float* __restrict__ E, const int* __restrict__ labels,
     const float* __restrict__ sq, const float* __restrict__ apw, const int* __restrict__ hpw,
     const int* __restrict__ anypw, float* __restrict__ partials){
  __shared__ float4 At[MI*68 + 4];
  __shared__ float redv[4][MI]; __shared__ int redj[4][MI]; __shared__ int redsm[4][MI];
  __shared__ int finNeg[MI]; __shared__ int finVal[MI];
  __shared__ float redp[4], redn[4];
  int t=threadIdx.x, lane=t&63, w=t>>6;
  int a0 = blockIdx.x * MI;
  const float4* E4 = (const float4*)E;
  for (int idx=t; idx<MI*64; idx+=256){
    int a=idx>>6, q=idx&63, pp=q&3, mm=q>>2;
    At[a*68 + pp*17 + mm] = E4[(size_t)(a0+a)*D4 + q];
  }
  __syncthreads();
  float apv[MI], sqi[MI]; int labi[MI];
  #pragma unroll
  for (int a=0;a<MI;a++){ apv[a]=apw[a0+a]; sqi[a]=sq[a0+a]; labi[a]=labels[a0+a]; }
  float mnv[MI]; int mnj[MI]; int smj[MI];
  #pragma unroll
  for (int a=0;a<MI;a++){ mnv[a]=INFINITY; mnj[a]=0; smj[a]=IMAX; }
  int s = t>>2, p = t&3;
  for (int it=0; it<16; it++){
    int colb = it*256 + 4*s;
    const float4* __restrict__ bp = E4 + (size_t)colb*D4 + p;
    float acc[MI][4];
    #pragma unroll
    for (int a=0;a<MI;a++){
      #pragma unroll
      for (int c2=0;c2<4;c2++) acc[a][c2]=0.0f;
    }
    for (int mg=0; mg<4; mg++){
      float4 b[4][4];
      #pragma unroll
      for (int c2=0;c2<4;c2++){
        #pragma unroll
        for (int m=0;m<4;m++) b[m][c2] = bp[(size_t)c2*D4 + mg*16 + m*4];
      }
      #pragma unroll
      for (int a=0;a<MI;a++){
        float4 a4[4];
        #pragma unroll
        for (int m=0;m<4;m++) a4[m] = At[a*68 + p*17 + mg*4 + m];
        #pragma unroll
        for (int m=0;m<4;m++){
          #pragma unroll
          for (int c2=0;c2<4;c2++) acc[a][c2] = fma4(a4[m], b[m][c2], acc[a][c2]);
        }
      }
    }
    #pragma unroll
    for (int a=0;a<MI;a++){
      #pragma unroll
      for (int c2=0;c2<4;c2++){
        float v = acc[a][c2];
        v += __shfl_xor(v,1); v += __shfl_xor(v,2);
        acc[a][c2] = v;
      }
    }
    #pragma unroll
    for (int c2=0;c2<4;c2++){
      int j = colb + c2;
      int lj = labels[j]; float sqj = sq[j];
      #pragma unroll
      for (int a=0;a<MI;a++){
        float d = sqrtf(fmaxf(sqi[a]+sqj-2.0f*acc[a][c2], 0.0f));
        if (lj != labi[a]){
          if (d < mnv[a]){ mnv[a]=d; mnj[a]=j; }
          if (d > apv[a] && d < apv[a]+MARGINF && j < smj[a]) smj[a]=j;
        }
      }
    }
  }
  #pragma unroll
  for (int a=0;a<MI;a++){
    float v=mnv[a]; int j=mnj[a]; int sm=smj[a];
    #pragma unroll
    for (int off=32; off; off>>=1){
      float v2=__shfl_xor(v,off); int j2=__shfl_xor(j,off); int s2=__shfl_xor(sm,off);
      if (v2<v || (v2==v && j2<j)){ v=v2; j=j2; }
      sm = (s2<sm)?s2:sm;
    }
    if (lane==0){ redv[w][a]=v; redj[w][a]=j; redsm[w][a]=sm; }
  }
  __syncthreads();
  if (t < MI){
    int a=t;
    float V=INFINITY; int J=0; int S=IMAX; bool first=true;
    for (int q=0;q<4;q++){
      float v2=redv[q][a]; int j2=redj[q][a];
      if (first || v2<V || (v2==V && j2<J)){ V=v2; J=j2; first=false; }
      int s2=redsm[q][a]; S=(s2<S)?s2:S;
    }
    bool anyneg = (V < INFINITY);
    finNeg[a] = (S != IMAX) ? S : J;
    finVal[a] = (anypw[a0+a] != 0 && anyneg) ? 1 : 0;
  }
  __syncthreads();
  float lsum=0.0f, lcnt=0.0f;
  for (int a=0;a<MI;a++){
    if (finVal[a]){
      int hp = hpw[a0+a]; int ng = finNeg[a];
      float ai = E[(size_t)(a0+a)*DIM + t];
      float pv = E[(size_t)hp*DIM + t];
      float nv = E[(size_t)ng*DIM + t];
      float dp = ai - pv + EPSF; float dn = ai - nv + EPSF;
      float sp = dp*dp, sn = dn*dn;
      #pragma unroll
      for (int off=32; off; off>>=1){ sp += __shfl_xor(sp,off); sn += __shfl_xor(sn,off); }
      if (lane==0){ redp[w]=sp; redn[w]=sn; }
    }
    __syncthreads();
    if (finVal[a] && t==0){
      float SP=(redp[0]+redp[1])+(redp[2]+redp[3]);
      float SN=(redn[0]+redn[1])+(redn[2]+redn[3]);
      lsum += fmaxf(sqrtf(SP)-sqrtf(SN)+MARGINF, 0.0f);
      lcnt += 1.0f;
    }
    __syncthreads();
  }
  if (t==0){ partials[2*blockIdx.x]=lsum; partials[2*blockIdx.x+1]=lcnt; }
}

__global__ __launch_bounds__(256) void k_fin(const float* __restrict__ partials, float* __restrict__ out, int nb){
  __shared__ float rs[4], rc[4];
  int t=threadIdx.x, lane=t&63, w=t>>6;
  float s=0.f, c=0.f;
  for (int q=t;q<nb;q+=256){ s+=partials[2*q]; c+=partials[2*q+1]; }
  #pragma unroll
  for (int off=32; off; off>>=1){ s+=__shfl_xor(s,off); c+=__shfl_xor(c,off); }
  if (lane==0){ rs[w]=s; rc[w]=c; }
  __syncthreads();
  if (t==0){
    float S=(rs[0]+rs[1])+(rs[2]+rs[3]);
    float C=(rc[0]+rc[1])+(rc[2]+rc[3]);
    out[0] = (C>0.0f) ? S/fmaxf(C,1.0f) : 0.0f;
  }
}

extern "C" void kernel_launch(void* const* d_in, const int* in_sizes, int n_in,
                              void* d_out, int out_size, void* d_ws, size_t ws_size,
                              hipStream_t stream) {
  const float* E      = (const float*)d_in[0];   // 4096x256 fp32
  const int*   labels = (const int*)d_in[1];     // 4096 int32
  float* out = (float*)d_out;

  float* sqw      = (float*)d_ws;          // 4096 f
  float* apw      = sqw + BN;              // 4096 f   (fallback only)
  int*   hpw      = (int*)(apw + BN);      // 4096 i   (fallback only)
  int*   anypw    = hpw + BN;              // 4096 i   (fallback only)
  float* partials = (float*)(anypw + BN);  // 1024 f
  unsigned int* counter = (unsigned int*)(partials + 1024);
  unsigned short* EhiT = (unsigned short*)((char*)d_ws + 131072);       // 2 MB (tiled)
  unsigned short* EloT = EhiT + (size_t)BN*DIM;                         // 2 MB (tiled)
  bool big = ws_size >= (size_t)(131072 + 4*1024*1024);

  if (big){
    k_pre2  <<<64,    256,  0, stream>>>(E, EhiT, EloT, sqw, counter);
    k_main_m<<<BN/MT, 1024, 0, stream>>>(E, EhiT, EloT, labels, sqw, partials, counter, out);
  } else {
    k_sq  <<<BN/256, 256, 0, stream>>>(E, sqw);
    k_pos <<<256,    256, 0, stream>>>(E, labels, sqw, apw, hpw, anypw);
    k_main<<<BN/MI,  256, 0, stream>>>(E, labels, sqw, apw, hpw, anypw, partials);
    k_fin <<<1,      256, 0, stream>>>(partials, out, BN/MI);
  }
}